// Round 3
// baseline (910.530 us; speedup 1.0000x reference)
//
#include <hip/hip_runtime.h>

#define F_IN 128
#define F_OUT 64
#define ROWS_PER_BLOCK 64

#define NPB 128          // nodes per bucket (128*64*4B = 32 KB LDS accumulator)
#define NPB_SHIFT 7
#define BCAP 800         // max buckets supported by LDS histogram
#define CUR_STRIDE 16    // pad cursors to one 64B line each (atomic contention)

// ---------------------------------------------------------------------------
// Kernel 1: support = x @ weight   (fp32 vector-ALU GEMM; no fp32 MFMA on CDNA4)
// ---------------------------------------------------------------------------
__global__ __launch_bounds__(256) void gemm_kernel(const float* __restrict__ x,
                                                   const float* __restrict__ w,
                                                   float* __restrict__ support,
                                                   int n_nodes) {
    __shared__ float w_lds[F_IN * F_OUT];                 // 32 KB
    __shared__ float x_lds[ROWS_PER_BLOCK][F_IN + 1];     // ~33 KB

    const int tid = threadIdx.x;

    {
        const float4* w4 = (const float4*)w;
        float4* wl4 = (float4*)w_lds;
        #pragma unroll
        for (int i = tid; i < (F_IN * F_OUT) / 4; i += 256) wl4[i] = w4[i];
    }

    const int row0 = blockIdx.x * ROWS_PER_BLOCK;

    #pragma unroll
    for (int i = tid; i < ROWS_PER_BLOCK * (F_IN / 4); i += 256) {
        const int r   = i >> 5;
        const int k4  = i & 31;
        const int row = row0 + r;
        float4 v = make_float4(0.f, 0.f, 0.f, 0.f);
        if (row < n_nodes) v = ((const float4*)(x + (size_t)row * F_IN))[k4];
        x_lds[r][k4 * 4 + 0] = v.x;
        x_lds[r][k4 * 4 + 1] = v.y;
        x_lds[r][k4 * 4 + 2] = v.z;
        x_lds[r][k4 * 4 + 3] = v.w;
    }
    __syncthreads();

    const int tf = tid & 15;
    const int tr = tid >> 4;

    float acc[4][4] = {};
    #pragma unroll 4
    for (int k = 0; k < F_IN; ++k) {
        const float4 wv = *(const float4*)&w_lds[k * F_OUT + 4 * tf];
        const float x0 = x_lds[4 * tr + 0][k];
        const float x1 = x_lds[4 * tr + 1][k];
        const float x2 = x_lds[4 * tr + 2][k];
        const float x3 = x_lds[4 * tr + 3][k];
        acc[0][0] += x0 * wv.x; acc[0][1] += x0 * wv.y; acc[0][2] += x0 * wv.z; acc[0][3] += x0 * wv.w;
        acc[1][0] += x1 * wv.x; acc[1][1] += x1 * wv.y; acc[1][2] += x1 * wv.z; acc[1][3] += x1 * wv.w;
        acc[2][0] += x2 * wv.x; acc[2][1] += x2 * wv.y; acc[2][2] += x2 * wv.z; acc[2][3] += x2 * wv.w;
        acc[3][0] += x3 * wv.x; acc[3][1] += x3 * wv.y; acc[3][2] += x3 * wv.z; acc[3][3] += x3 * wv.w;
    }

    #pragma unroll
    for (int i = 0; i < 4; ++i) {
        const int row = row0 + 4 * tr + i;
        if (row < n_nodes) {
            float4 v = make_float4(acc[i][0], acc[i][1], acc[i][2], acc[i][3]);
            *(float4*)&support[(size_t)row * F_OUT + 4 * tf] = v;
        }
    }
}

// ---------------------------------------------------------------------------
// Kernel 2: bucket histogram of dst>>7. LDS hist per block, one global
// atomicAdd per (block, nonempty bucket) flush.
// ---------------------------------------------------------------------------
__global__ __launch_bounds__(256) void hist_kernel(const int* __restrict__ edge_dst,
                                                   int* __restrict__ g_hist,
                                                   int n_edges, int nbuckets) {
    __shared__ int h[BCAP];
    for (int i = threadIdx.x; i < BCAP; i += 256) h[i] = 0;
    __syncthreads();

    const int n4 = n_edges >> 2;
    const int4* d4 = (const int4*)edge_dst;
    const int stride = gridDim.x * blockDim.x;
    for (int t = blockIdx.x * blockDim.x + threadIdx.x; t < n4; t += stride) {
        const int4 d = d4[t];
        atomicAdd(&h[d.x >> NPB_SHIFT], 1);
        atomicAdd(&h[d.y >> NPB_SHIFT], 1);
        atomicAdd(&h[d.z >> NPB_SHIFT], 1);
        atomicAdd(&h[d.w >> NPB_SHIFT], 1);
    }
    if (blockIdx.x == 0) {   // tail edges
        for (int e = (n4 << 2) + threadIdx.x; e < n_edges; e += 256)
            atomicAdd(&h[edge_dst[e] >> NPB_SHIFT], 1);
    }
    __syncthreads();
    for (int i = threadIdx.x; i < nbuckets; i += 256)
        if (h[i]) atomicAdd(&g_hist[i], h[i]);
}

// ---------------------------------------------------------------------------
// Kernel 3: single-block exclusive scan of nbuckets (<=1024) counts.
// Writes offsets[0..nb] and initializes padded cursors to offsets.
// ---------------------------------------------------------------------------
__global__ __launch_bounds__(256) void scan_kernel(const int* __restrict__ g_hist,
                                                   int* __restrict__ offsets,
                                                   int* __restrict__ cursors,
                                                   int nb) {
    __shared__ int lds[256];
    const int tid = threadIdx.x;
    const int base = tid * 4;

    const int v0 = (base + 0 < nb) ? g_hist[base + 0] : 0;
    const int v1 = (base + 1 < nb) ? g_hist[base + 1] : 0;
    const int v2 = (base + 2 < nb) ? g_hist[base + 2] : 0;
    const int v3 = (base + 3 < nb) ? g_hist[base + 3] : 0;
    const int s1 = v0, s2 = s1 + v1, s3 = s2 + v2, s4 = s3 + v3;

    int t = s4;
    lds[tid] = t;
    __syncthreads();
    #pragma unroll
    for (int off = 1; off < 256; off <<= 1) {
        const int xv = (tid >= off) ? lds[tid - off] : 0;
        __syncthreads();
        t += xv;
        lds[tid] = t;
        __syncthreads();
    }
    const int excl = t - s4;
    const int e0 = excl, e1 = excl + s1, e2 = excl + s2, e3 = excl + s3;
    if (base + 0 < nb) { offsets[base + 0] = e0; cursors[(base + 0) * CUR_STRIDE] = e0; }
    if (base + 1 < nb) { offsets[base + 1] = e1; cursors[(base + 1) * CUR_STRIDE] = e1; }
    if (base + 2 < nb) { offsets[base + 2] = e2; cursors[(base + 2) * CUR_STRIDE] = e2; }
    if (base + 3 < nb) { offsets[base + 3] = e3; cursors[(base + 3) * CUR_STRIDE] = e3; }
    if (tid == 255) offsets[nb] = t;   // grand total = n_edges
}

// ---------------------------------------------------------------------------
// Kernel 4: multisplit scatter into bucket-grouped order.
// sorted[pos].x = src | (dstLocal << 20)   (requires n_nodes < 2^20)
// sorted[pos].y = val bits
// Sequential position allocation per bucket -> write frontier ~nb lines only,
// so stores assemble full 64B lines in L2 (no write amplification).
// ---------------------------------------------------------------------------
__global__ __launch_bounds__(256) void bscatter_kernel(const float* __restrict__ edge_val,
                                                       const int* __restrict__ edge_src,
                                                       const int* __restrict__ edge_dst,
                                                       int* __restrict__ cursors,
                                                       int2* __restrict__ sorted,
                                                       int n_edges) {
    const int n4 = n_edges >> 2;
    const int stride = gridDim.x * blockDim.x;
    const int4*   s4 = (const int4*)edge_src;
    const int4*   d4 = (const int4*)edge_dst;
    const float4* v4 = (const float4*)edge_val;

    for (int t = blockIdx.x * blockDim.x + threadIdx.x; t < n4; t += stride) {
        const int4   s = s4[t];
        const int4   d = d4[t];
        const float4 v = v4[t];
        int b, pos;
        b = d.x >> NPB_SHIFT; pos = atomicAdd(&cursors[b * CUR_STRIDE], 1);
        sorted[pos] = make_int2(s.x | ((d.x & (NPB - 1)) << 20), __float_as_int(v.x));
        b = d.y >> NPB_SHIFT; pos = atomicAdd(&cursors[b * CUR_STRIDE], 1);
        sorted[pos] = make_int2(s.y | ((d.y & (NPB - 1)) << 20), __float_as_int(v.y));
        b = d.z >> NPB_SHIFT; pos = atomicAdd(&cursors[b * CUR_STRIDE], 1);
        sorted[pos] = make_int2(s.z | ((d.z & (NPB - 1)) << 20), __float_as_int(v.z));
        b = d.w >> NPB_SHIFT; pos = atomicAdd(&cursors[b * CUR_STRIDE], 1);
        sorted[pos] = make_int2(s.w | ((d.w & (NPB - 1)) << 20), __float_as_int(v.w));
    }
    if (blockIdx.x == 0 && threadIdx.x == 0) {   // tail edges (scalar, <=3)
        for (int e = n4 << 2; e < n_edges; ++e) {
            const int dd = edge_dst[e];
            const int b2 = dd >> NPB_SHIFT;
            const int p2 = atomicAdd(&cursors[b2 * CUR_STRIDE], 1);
            sorted[p2] = make_int2(edge_src[e] | ((dd & (NPB - 1)) << 20),
                                   __float_as_int(edge_val[e]));
        }
    }
}

// ---------------------------------------------------------------------------
// Kernel 5: per-bucket accumulate. One block per bucket; 512 threads = 8 waves;
// lane = feature (64 = wave width -> 256B coalesced support-row read).
// LDS fp32 atomics (banks f, f+32 -> 2-way aliasing = free). ReLU fused.
// 2-stage software pipeline hides the sorted->support dependent chain.
// ---------------------------------------------------------------------------
__global__ __launch_bounds__(512) void baccum_kernel(const float* __restrict__ support,
                                                     const int2* __restrict__ sorted,
                                                     const int* __restrict__ offsets,
                                                     float* __restrict__ out,
                                                     int n_nodes) {
    __shared__ float acc[NPB * F_OUT];   // 32 KB
    const int tid = threadIdx.x;
    float4* acc4 = (float4*)acc;
    #pragma unroll
    for (int i = tid; i < NPB * F_OUT / 4; i += 512)
        acc4[i] = make_float4(0.f, 0.f, 0.f, 0.f);
    __syncthreads();

    const int bucket = blockIdx.x;
    const int beg = offsets[bucket];
    const int end = offsets[bucket + 1];
    const int w = tid >> 6;   // wave 0..7
    const int f = tid & 63;   // feature

    int i = beg + w;
    int2 ev = make_int2(0, 0);
    float s = 0.f;
    if (i < end) {
        ev = sorted[i];
        s = support[(size_t)(ev.x & 0xFFFFF) * F_OUT + f];
    }
    while (i < end) {
        const int j = i + 8;
        int2 evn = make_int2(0, 0);
        float sn = 0.f;
        if (j < end) {
            evn = sorted[j];
            sn = support[(size_t)(evn.x & 0xFFFFF) * F_OUT + f];
        }
        atomicAdd(&acc[(((unsigned)ev.x) >> 20) * F_OUT + f], __int_as_float(ev.y) * s);
        ev = evn; s = sn; i = j;
    }
    __syncthreads();

    const int base = bucket << NPB_SHIFT;
    const int nrows = min(NPB, n_nodes - base);
    float4* out4 = (float4*)(out + (size_t)base * F_OUT);
    const int lim = nrows * (F_OUT / 4);
    for (int i2 = tid; i2 < lim; i2 += 512) {
        float4 v = acc4[i2];
        v.x = fmaxf(v.x, 0.f); v.y = fmaxf(v.y, 0.f);
        v.z = fmaxf(v.z, 0.f); v.w = fmaxf(v.w, 0.f);
        out4[i2] = v;
    }
}

// ---------------------------------------------------------------------------
// Fallback (ws too small / shapes out of packing range): round-1 atomic path.
// ---------------------------------------------------------------------------
__global__ __launch_bounds__(256) void scatter_kernel(const float* __restrict__ support,
                                                      const float* __restrict__ edge_val,
                                                      const int* __restrict__ edge_src,
                                                      const int* __restrict__ edge_dst,
                                                      float* __restrict__ out,
                                                      int n_edges) {
    const long gid = (long)blockIdx.x * blockDim.x + threadIdx.x;
    const int e = (int)(gid >> 4);
    if (e >= n_edges) return;
    const int fo = (int)(gid & 15) * 4;
    const int src   = edge_src[e];
    const int dst   = edge_dst[e];
    const float val = edge_val[e];
    const float4 s = *(const float4*)&support[(size_t)src * F_OUT + fo];
    float* o = &out[(size_t)dst * F_OUT + fo];
    atomicAdd(o + 0, val * s.x);
    atomicAdd(o + 1, val * s.y);
    atomicAdd(o + 2, val * s.z);
    atomicAdd(o + 3, val * s.w);
}

__global__ __launch_bounds__(256) void relu_kernel(float* __restrict__ out, int n4) {
    const int i = blockIdx.x * blockDim.x + threadIdx.x;
    if (i < n4) {
        float4 v = ((float4*)out)[i];
        v.x = fmaxf(v.x, 0.f); v.y = fmaxf(v.y, 0.f);
        v.z = fmaxf(v.z, 0.f); v.w = fmaxf(v.w, 0.f);
        ((float4*)out)[i] = v;
    }
}

extern "C" void kernel_launch(void* const* d_in, const int* in_sizes, int n_in,
                              void* d_out, int out_size, void* d_ws, size_t ws_size,
                              hipStream_t stream) {
    const float* x        = (const float*)d_in[0];
    const float* w        = (const float*)d_in[1];
    const float* edge_val = (const float*)d_in[2];
    const int*   edge_src = (const int*)d_in[3];
    const int*   edge_dst = (const int*)d_in[4];
    float* out = (float*)d_out;

    const int n_nodes = in_sizes[0] / F_IN;   // 100000
    const int n_edges = in_sizes[2];          // 1600000
    const int nb = (n_nodes + NPB - 1) >> NPB_SHIFT;   // 782 buckets

    // Workspace layout:
    //   support : n_nodes*F_OUT floats   (25.6 MB)
    //   sorted  : n_edges int2           (12.8 MB)
    //   offsets : (nb+1) ints
    //   cursors : nb*CUR_STRIDE ints     (line-padded)
    //   hist    : nb ints
    char* p = (char*)d_ws;
    float* support = (float*)p;  p += (size_t)n_nodes * F_OUT * sizeof(float);
    int2*  sorted  = (int2*)p;   p += (size_t)n_edges * sizeof(int2);
    int*   offsets = (int*)p;    p += (size_t)(nb + 1) * sizeof(int);
    int*   cursors = (int*)p;    p += (size_t)nb * CUR_STRIDE * sizeof(int);
    int*   g_hist  = (int*)p;    p += (size_t)nb * sizeof(int);
    const size_t ws_needed = (size_t)(p - (char*)d_ws);

    const int gemm_blocks = (n_nodes + ROWS_PER_BLOCK - 1) / ROWS_PER_BLOCK;
    gemm_kernel<<<gemm_blocks, 256, 0, stream>>>(x, w, support, n_nodes);

    const bool ok = (ws_size >= ws_needed) && (nb <= BCAP) && (n_nodes < (1 << 20));
    if (ok) {
        hipMemsetAsync(g_hist, 0, (size_t)nb * sizeof(int), stream);
        hist_kernel<<<256, 256, 0, stream>>>(edge_dst, g_hist, n_edges, nb);
        scan_kernel<<<1, 256, 0, stream>>>(g_hist, offsets, cursors, nb);
        bscatter_kernel<<<1024, 256, 0, stream>>>(edge_val, edge_src, edge_dst,
                                                  cursors, sorted, n_edges);
        baccum_kernel<<<nb, 512, 0, stream>>>(support, sorted, offsets, out, n_nodes);
    } else {
        hipMemsetAsync(d_out, 0, (size_t)out_size * sizeof(float), stream);
        const long st = (long)n_edges * 16;
        scatter_kernel<<<(int)((st + 255) / 256), 256, 0, stream>>>(
            support, edge_val, edge_src, edge_dst, out, n_edges);
        const int n4o = out_size / 4;
        relu_kernel<<<(n4o + 255) / 256, 256, 0, stream>>>(out, n4o);
    }
}